// Round 11
// baseline (165.225 us; speedup 1.0000x reference)
//
#include <hip/hip_runtime.h>
#include <hip/hip_bf16.h>

// x: [B=1024, N=65536] f32, index: [N] i32 permutation, group size 64.
#define BATCH   1024
#define NEUR    65536
#define NGRP    1024                  // groups (thread t owns group t)
#define BLK     1024
#define NCHUNK  4
#define CHUNK   (NEUR / NCHUNK)       // 16384 floats per chunk (64 KB LDS)
#define CHUNK_F4 (CHUNK / 4)
#define F4T     (CHUNK_F4 / BLK)      // 4 float4 per thread
#define KMAX    24                    // padded slots per (chunk, group) cell
#define SENT    CHUNK                 // sentinel LDS slot holding 0.0f
#define ROW_F4  (NEUR / 4)            // 16384
#define Q_F4    (ROW_F4 / 4)          // 4096 float4 per quarter-row
#define Q_ITERS (Q_F4 / BLK)          // 4
#define BUCKET_ELEMS (NCHUNK * NGRP * KMAX)   // 98304 u16 (transposed layout)
#define SPILL_CAP 1024
#define NSUM    (BATCH * NGRP)

typedef float          f32x4 __attribute__((ext_vector_type(4)));
typedef unsigned short u16x8 __attribute__((ext_vector_type(8)));
typedef unsigned short u16x4 __attribute__((ext_vector_type(4)));

// ws: [gof u16 128 KB][bucket 192 KB][part 16 MB][spill 4 KB]

__global__ void init_tables(unsigned short* __restrict__ bucket,
                            unsigned int* __restrict__ spill) {
    int i = blockIdx.x * blockDim.x + threadIdx.x;
    if (i < BUCKET_ELEMS) bucket[i] = (unsigned short)SENT;
    if (i == 0) spill[0] = 0;          // re-zero every call (graph replay)
}

// Wave == one group. Ballot/popcount slots each member into its source-chunk
// cell (transposed: [cell][slot] so k1 reads 3x contiguous ushort8). Group
// table is u16 now (R11: int32 gof cost k3 256 MB of table traffic — as much
// as the x stream itself).
__global__ void build_tables(const int* __restrict__ index,
                             unsigned short* __restrict__ gof,
                             unsigned short* __restrict__ bucket,
                             unsigned int* __restrict__ spill) {
    const int p    = blockIdx.x * blockDim.x + threadIdx.x;
    const int lane = threadIdx.x & 63;
    const int g    = p >> 6;
    const int s    = index[p];
    gof[s] = (unsigned short)g;
    const int c = s / CHUNK;
    unsigned long long mc = 0;
    #pragma unroll
    for (int cc = 0; cc < NCHUNK; ++cc) {
        unsigned long long m = __ballot(c == cc);
        if (cc == c) mc = m;
    }
    const int k = __popcll(mc & ((1ull << lane) - 1ull));
    if (k < KMAX) {
        bucket[((size_t)(c * NGRP + g)) * KMAX + k] = (unsigned short)(s & (CHUNK - 1));
    } else {
        unsigned int pos = atomicAdd(spill, 1u);
        if (pos < SPILL_CAP - 1)
            spill[1 + pos] = ((unsigned)g << 16) | (unsigned)s;  // s carries chunk
    }
}

// k1: one block per (row, chunk). Stage 64 KB chunk, one barrier, 24
// branch-free sentinel-padded gather-adds (3x ushort8 slot loads), spill
// fixup FROM LDS (R11: moved off k3's critical path — k3 was doing ~40
// serialized global scalar loads per block), one plain coalesced store.
__global__ __launch_bounds__(BLK, 8)
void k1_partial(const float* __restrict__ x,
                const unsigned short* __restrict__ bucket,
                const unsigned int* __restrict__ spill,
                float* __restrict__ part) {
    __shared__ float xs[CHUNK + 16];
    const int bc = blockIdx.x;
    const int b  = bc >> 2;            // row
    const int c  = bc & 3;             // chunk
    const int t  = threadIdx.x;

    if (t == 0) xs[SENT] = 0.0f;

    const float4* __restrict__ src =
        (const float4*)(x + (size_t)b * NEUR + (size_t)c * CHUNK);
    #pragma unroll
    for (int i = 0; i < F4T; ++i) ((float4*)xs)[i * BLK + t] = src[i * BLK + t];
    __syncthreads();

    const unsigned short* __restrict__ bk =
        bucket + ((size_t)(c * NGRP + t)) * KMAX;          // 48 B contiguous
    const u16x8 w0 = *(const u16x8*)(bk);
    const u16x8 w1 = *(const u16x8*)(bk + 8);
    const u16x8 w2 = *(const u16x8*)(bk + 16);

    float a0 = 0.0f, a1 = 0.0f;
    #pragma unroll
    for (int j = 0; j < 8; ++j) {
        a0 += xs[w0[j]];
        a1 += xs[w1[j]];
        a0 += xs[w2[j]];               // pads hit the 0.0 sentinel
    }

    // Spill entries for THIS chunk: read from LDS (cheap), add to my partial.
    const unsigned int ns = spill[0];  // ~40 entries, wave-uniform scan
    for (unsigned int e = 0; e < ns; ++e) {
        const unsigned int ent = spill[1 + e];
        if ((int)(ent >> 16) == t && (int)((ent >> 14) & 3u) == c)
            a1 += xs[ent & 0x3FFFu];
    }

    part[((size_t)b * NCHUNK + c) * NGRP + t] = a0 + a1;   // coalesced
}

// k3: one block per QUARTER-row (4096 blocks), reverse order so the
// L3-hottest rows go first. Contiguous 16 KB partial read, reciprocal,
// then the proven coalesced scale + nontemporal store (u16 group ids).
__global__ __launch_bounds__(BLK, 8)
void k3_scale(const float* __restrict__ x,
              const unsigned short* __restrict__ gof,
              const float* __restrict__ part,
              float* __restrict__ out) {
    __shared__ float rsum[NGRP];       // 4 KB only
    const int rb = blockIdx.x;
    const int b  = (BATCH - 1) - (rb >> 2);
    const int q  = rb & 3;
    const int t  = threadIdx.x;

    const float* __restrict__ prow = part + (size_t)b * NCHUNK * NGRP;
    float s = prow[t] + prow[NGRP + t] + prow[2 * NGRP + t] + prow[3 * NGRP + t];
    rsum[t] = 1.0f / s;
    __syncthreads();

    const float4* __restrict__ xrow4 = (const float4*)(x + (size_t)b * NEUR);
    const u16x4*  __restrict__ gof4  = (const u16x4*)gof;  // per-float4 ids, 8 B
    f32x4*        __restrict__ orow4 = (f32x4*)(out + (size_t)b * NEUR);

    #pragma unroll
    for (int it = 0; it < Q_ITERS; ++it) {
        const int e = q * Q_F4 + it * BLK + t;
        const float4 v = xrow4[e];     // L3-hot re-read
        const u16x4 g = gof4[e];       // 128 KB table (was 256 KB), L2-resident
        f32x4 o;
        o.x = v.x * rsum[g.x];
        o.y = v.y * rsum[g.y];
        o.z = v.z * rsum[g.z];
        o.w = v.w * rsum[g.w];
        __builtin_nontemporal_store(o, &orow4[e]);  // don't evict x from L3
    }
}

extern "C" void kernel_launch(void* const* d_in, const int* in_sizes, int n_in,
                              void* d_out, int out_size, void* d_ws, size_t ws_size,
                              hipStream_t stream) {
    const float* x     = (const float*)d_in[0];
    const int*   index = (const int*)d_in[1];
    float*       out   = (float*)d_out;

    unsigned short* gof    = (unsigned short*)d_ws;                 // 128 KB
    unsigned short* bucket = gof + NEUR;                            // 192 KB
    float*          part   = (float*)(bucket + BUCKET_ELEMS);       // 16 MB
    unsigned int*   spill  = (unsigned int*)(part + (size_t)BATCH * NCHUNK * NGRP);

    init_tables<<<BUCKET_ELEMS / BLK, BLK, 0, stream>>>(bucket, spill);
    build_tables<<<NEUR / BLK, BLK, 0, stream>>>(index, gof, bucket, spill);
    k1_partial<<<BATCH * NCHUNK, BLK, 0, stream>>>(x, bucket, spill, part);
    k3_scale<<<BATCH * 4, BLK, 0, stream>>>(x, gof, part, out);
}

// Round 12
// 164.119 us; speedup vs baseline: 1.0067x; 1.0067x over previous
//
#include <hip/hip_runtime.h>
#include <hip/hip_bf16.h>

// x: [B=1024, N=65536] f32, index: [N] i32 permutation, group size 64.
#define BATCH   1024
#define NEUR    65536
#define NGRP    1024                  // groups (thread t owns group t)
#define BLK     1024
#define NCHUNK  4
#define CHUNK   (NEUR / NCHUNK)       // 16384 floats per chunk (64 KB LDS)
#define CHUNK_F4 (CHUNK / 4)
#define F4T     (CHUNK_F4 / BLK)      // 4 float4 per thread
#define KMAX    24                    // padded slots per (chunk, group) cell
#define SENT    CHUNK                 // sentinel LDS slot holding 0.0f
#define ROW_F4  (NEUR / 4)            // 16384
#define HALF_F4 (ROW_F4 / 2)          // 8192
#define H_ITERS (HALF_F4 / BLK)       // 8
#define BUCKET_ELEMS (NCHUNK * NGRP * KMAX)   // 98304 u16 (transposed layout)
#define SPILL_CAP 1024

typedef float          f32x4 __attribute__((ext_vector_type(4)));
typedef unsigned short u16x8 __attribute__((ext_vector_type(8)));
typedef unsigned short u16x4 __attribute__((ext_vector_type(4)));

// ws: [gof u16 128 KB][bucket 192 KB][part 16 MB][spill 4 KB]

// Wave == one group (64 consecutive permuted positions). Ballot/popcount
// slots each member into its source-chunk cell (transposed [cell][slot] so
// k1 reads 3 contiguous ushort8). The wave ALSO writes its own cells' pad
// sentinels (folds the old init kernel away — R12). Overflow -> spill list.
__global__ void build_tables(const int* __restrict__ index,
                             unsigned short* __restrict__ gof,
                             unsigned short* __restrict__ bucket,
                             unsigned int* __restrict__ spill) {
    const int p    = blockIdx.x * blockDim.x + threadIdx.x;
    const int lane = threadIdx.x & 63;
    const int g    = p >> 6;
    const int s    = index[p];
    gof[s] = (unsigned short)g;
    const int c = s / CHUNK;
    unsigned long long mc = 0;
    int count[NCHUNK];
    #pragma unroll
    for (int cc = 0; cc < NCHUNK; ++cc) {
        unsigned long long m = __ballot(c == cc);
        if (cc == c) mc = m;
        count[cc] = __popcll(m);
    }
    const int k = __popcll(mc & ((1ull << lane) - 1ull));
    if (k < KMAX) {
        bucket[((size_t)(c * NGRP + g)) * KMAX + k] = (unsigned short)(s & (CHUNK - 1));
    } else {
        unsigned int pos = atomicAdd(spill, 1u);
        if (pos < SPILL_CAP - 1)
            spill[1 + pos] = ((unsigned)g << 16) | (unsigned)s;  // s carries chunk
    }
    // Pad slots k in [count_c, KMAX) get the sentinel; lanes cover 96 slots.
    #pragma unroll
    for (int j = 0; j < 2; ++j) {
        const int slot = lane + j * 64;
        if (slot < NCHUNK * KMAX) {
            const int cc = slot / KMAX, kk = slot % KMAX;
            if (kk >= count[cc])
                bucket[((size_t)(cc * NGRP + g)) * KMAX + kk] = (unsigned short)SENT;
        }
    }
}

// k1: one block per (row, chunk). Stage 64 KB chunk, one barrier, 24
// branch-free sentinel-padded gather-adds (3x ushort8 slot loads), spill
// fixup from LDS, one plain coalesced partial store (no atomics).
__global__ __launch_bounds__(BLK, 8)
void k1_partial(const float* __restrict__ x,
                const unsigned short* __restrict__ bucket,
                const unsigned int* __restrict__ spill,
                float* __restrict__ part) {
    __shared__ float xs[CHUNK + 16];
    const int bc = blockIdx.x;
    const int b  = bc >> 2;            // row
    const int c  = bc & 3;             // chunk
    const int t  = threadIdx.x;

    if (t == 0) xs[SENT] = 0.0f;

    const float4* __restrict__ src =
        (const float4*)(x + (size_t)b * NEUR + (size_t)c * CHUNK);
    #pragma unroll
    for (int i = 0; i < F4T; ++i) ((float4*)xs)[i * BLK + t] = src[i * BLK + t];
    __syncthreads();

    const unsigned short* __restrict__ bk =
        bucket + ((size_t)(c * NGRP + t)) * KMAX;          // 48 B contiguous
    const u16x8 w0 = *(const u16x8*)(bk);
    const u16x8 w1 = *(const u16x8*)(bk + 8);
    const u16x8 w2 = *(const u16x8*)(bk + 16);

    float a0 = 0.0f, a1 = 0.0f;
    #pragma unroll
    for (int j = 0; j < 8; ++j) {
        a0 += xs[w0[j]];
        a1 += xs[w1[j]];
        a0 += xs[w2[j]];               // pads hit the 0.0 sentinel
    }

    // Spill entries for THIS chunk: add from LDS (off k3's critical path).
    const unsigned int ns = spill[0];  // ~40 entries, wave-uniform scan
    for (unsigned int e = 0; e < ns; ++e) {
        const unsigned int ent = spill[1 + e];
        if ((int)(ent >> 16) == t && (int)((ent >> 14) & 3u) == c)
            a1 += xs[ent & 0x3FFFu];
    }

    part[((size_t)b * NCHUNK + c) * NGRP + t] = a0 + a1;   // coalesced
}

// k3: one block per HALF-row (2048 blocks — R10-proven granularity; R11's
// quarter-row doubled the prologue and regressed). Reverse order so the
// L3-hottest rows go first. Contiguous partial read, reciprocal, then the
// proven coalesced scale + nontemporal store (u16 group ids: 128 MB of
// table traffic instead of int32's 256 MB).
__global__ __launch_bounds__(BLK, 8)
void k3_scale(const float* __restrict__ x,
              const unsigned short* __restrict__ gof,
              const float* __restrict__ part,
              float* __restrict__ out) {
    __shared__ float rsum[NGRP];       // 4 KB only
    const int rb   = blockIdx.x;
    const int b    = (BATCH - 1) - (rb >> 1);
    const int half = rb & 1;
    const int t    = threadIdx.x;

    const float* __restrict__ prow = part + (size_t)b * NCHUNK * NGRP;
    float s = prow[t] + prow[NGRP + t] + prow[2 * NGRP + t] + prow[3 * NGRP + t];
    rsum[t] = 1.0f / s;
    __syncthreads();

    const float4* __restrict__ xrow4 = (const float4*)(x + (size_t)b * NEUR);
    const u16x4*  __restrict__ gof4  = (const u16x4*)gof;  // 8 B per float4
    f32x4*        __restrict__ orow4 = (f32x4*)(out + (size_t)b * NEUR);

    #pragma unroll
    for (int it = 0; it < H_ITERS; ++it) {
        const int e = half * HALF_F4 + it * BLK + t;
        const float4 v = xrow4[e];     // L3-hot re-read
        const u16x4 g = gof4[e];       // 128 KB table, L2-resident
        f32x4 o;
        o.x = v.x * rsum[g.x];
        o.y = v.y * rsum[g.y];
        o.z = v.z * rsum[g.z];
        o.w = v.w * rsum[g.w];
        __builtin_nontemporal_store(o, &orow4[e]);  // don't evict x from L3
    }
}

extern "C" void kernel_launch(void* const* d_in, const int* in_sizes, int n_in,
                              void* d_out, int out_size, void* d_ws, size_t ws_size,
                              hipStream_t stream) {
    const float* x     = (const float*)d_in[0];
    const int*   index = (const int*)d_in[1];
    float*       out   = (float*)d_out;

    unsigned short* gof    = (unsigned short*)d_ws;                 // 128 KB
    unsigned short* bucket = gof + NEUR;                            // 192 KB
    float*          part   = (float*)(bucket + BUCKET_ELEMS);       // 16 MB
    unsigned int*   spill  = (unsigned int*)(part + (size_t)BATCH * NCHUNK * NGRP);

    hipMemsetAsync(spill, 0, sizeof(unsigned int), stream);  // zero spill count
    build_tables<<<NEUR / BLK, BLK, 0, stream>>>(index, gof, bucket, spill);
    k1_partial<<<BATCH * NCHUNK, BLK, 0, stream>>>(x, bucket, spill, part);
    k3_scale<<<BATCH * 2, BLK, 0, stream>>>(x, gof, part, out);
}

// Round 13
// 149.044 us; speedup vs baseline: 1.1086x; 1.1011x over previous
//
#include <hip/hip_runtime.h>
#include <hip/hip_bf16.h>

// x: [B=1024, N=65536] f32, index: [N] i32 permutation, group size 64.
#define BATCH   1024
#define NEUR    65536
#define NGRP    1024
#define NCHUNK  8
#define CHUNK   (NEUR / NCHUNK)       // 8192 floats per chunk (32 KB LDS)
#define CHUNK_F4 (CHUNK / 4)          // 2048 float4
#define BLK1    512                   // k1 block: 4 blocks/CU (R13 lever)
#define F4T1    (CHUNK_F4 / BLK1)     // 4 float4 per thread
#define GPT     2                     // groups per k1 thread (t, t+512)
#define KMAX    16                    // padded slots per (chunk, group) cell
#define SENT    CHUNK                 // sentinel LDS slot holding 0.0f
#define BLK     1024                  // build/k3 block
#define ROW_F4  (NEUR / 4)            // 16384
#define HALF_F4 (ROW_F4 / 2)          // 8192
#define H_ITERS (HALF_F4 / BLK)       // 8
#define BUCKET_ELEMS (NCHUNK * NGRP * KMAX)   // 131072 u16 = 256 KB
#define SPILL_CAP 1024

typedef float          f32x4 __attribute__((ext_vector_type(4)));
typedef unsigned short u16x8 __attribute__((ext_vector_type(8)));
typedef unsigned short u16x4 __attribute__((ext_vector_type(4)));

// ws: [gof u16 128 KB][bucket 256 KB][part 32 MB][spill 4 KB]

// Wave == one group (64 consecutive permuted positions). Ballot/popcount
// slots each member into its source-chunk cell (transposed [cell][slot]);
// the wave also writes its own cells' pad sentinels (128 slots = 2 passes).
// Overflow (~25 entries chip-wide) -> spill list, handled in k1 from LDS.
__global__ void build_tables(const int* __restrict__ index,
                             unsigned short* __restrict__ gof,
                             unsigned short* __restrict__ bucket,
                             unsigned int* __restrict__ spill) {
    const int p    = blockIdx.x * blockDim.x + threadIdx.x;
    const int lane = threadIdx.x & 63;
    const int g    = p >> 6;
    const int s    = index[p];
    gof[s] = (unsigned short)g;
    const int c = s >> 13;                                 // s / CHUNK
    unsigned long long mc = 0;
    int count[NCHUNK];
    #pragma unroll
    for (int cc = 0; cc < NCHUNK; ++cc) {
        unsigned long long m = __ballot(c == cc);
        if (cc == c) mc = m;
        count[cc] = __popcll(m);
    }
    const int k = __popcll(mc & ((1ull << lane) - 1ull));
    if (k < KMAX) {
        bucket[((size_t)(c * NGRP + g)) * KMAX + k] = (unsigned short)(s & (CHUNK - 1));
    } else {
        unsigned int pos = atomicAdd(spill, 1u);
        if (pos < SPILL_CAP - 1)
            spill[1 + pos] = ((unsigned)g << 16) | (unsigned)s;  // s carries chunk
    }
    // Pad slots kk in [count_c, KMAX): 8 cells x 16 slots = 128 = 2 lane-passes.
    #pragma unroll
    for (int j = 0; j < 2; ++j) {
        const int slot = lane + j * 64;                    // 0..127
        const int cc = slot >> 4, kk = slot & 15;
        if (kk >= count[cc])
            bucket[((size_t)(cc * NGRP + g)) * KMAX + kk] = (unsigned short)SENT;
    }
}

// k1: one block per (row, chunk) — 8192 blocks, 512 threads, 32.8 KB LDS ->
// 4 blocks/CU (was 2): the HBM-staging phase of some blocks overlaps the
// LDS-gather phase of others on every CU (R13 theory: k1's stage->barrier->
// gather chain was the serialization). Thread t owns groups t and t+512.
__global__ __launch_bounds__(BLK1, 8)
void k1_partial(const float* __restrict__ x,
                const unsigned short* __restrict__ bucket,
                const unsigned int* __restrict__ spill,
                float* __restrict__ part) {
    __shared__ float xs[CHUNK + 16];   // 32 KB chunk + sentinel
    const int bc = blockIdx.x;
    const int b  = bc >> 3;            // row
    const int c  = bc & 7;             // chunk
    const int t  = threadIdx.x;

    if (t == 0) xs[SENT] = 0.0f;

    const float4* __restrict__ src =
        (const float4*)(x + (size_t)b * NEUR + (size_t)c * CHUNK);
    #pragma unroll
    for (int i = 0; i < F4T1; ++i) ((float4*)xs)[i * BLK1 + t] = src[i * BLK1 + t];
    __syncthreads();

    // 16 branch-free sentinel-padded gather-adds per owned group (2 groups).
    const unsigned short* __restrict__ bk0 =
        bucket + ((size_t)(c * NGRP + t)) * KMAX;          // 32 B contiguous
    const unsigned short* __restrict__ bk1 =
        bucket + ((size_t)(c * NGRP + t + 512)) * KMAX;
    const u16x8 w0 = *(const u16x8*)(bk0);
    const u16x8 w1 = *(const u16x8*)(bk0 + 8);
    const u16x8 w2 = *(const u16x8*)(bk1);
    const u16x8 w3 = *(const u16x8*)(bk1 + 8);

    float a0 = 0.0f, a1 = 0.0f, b0 = 0.0f, b1 = 0.0f;
    #pragma unroll
    for (int j = 0; j < 8; ++j) {
        a0 += xs[w0[j]];
        a1 += xs[w1[j]];
        b0 += xs[w2[j]];
        b1 += xs[w3[j]];               // pads hit the 0.0 sentinel
    }

    // Spill entries for THIS chunk: add from LDS (~25 chip-wide, wave scan).
    const unsigned int ns = spill[0];
    for (unsigned int e = 0; e < ns; ++e) {
        const unsigned int ent = spill[1 + e];
        if (((ent >> 13) & 7u) == (unsigned)c) {
            const float v = xs[ent & 0x1FFFu];
            const int gg = (int)(ent >> 16);
            if (gg == t)            a1 += v;
            else if (gg == t + 512) b1 += v;
        }
    }

    float* __restrict__ prow = part + ((size_t)b * NCHUNK + c) * NGRP;
    prow[t]       = a0 + a1;           // coalesced
    prow[t + 512] = b0 + b1;
}

// k3: one block per HALF-row (2048 blocks), reverse order so L3-hottest rows
// go first. 8 coalesced partial reads, reciprocal, then coalesced scale +
// nontemporal store (u16 group ids halve table traffic vs int32).
__global__ __launch_bounds__(BLK, 8)
void k3_scale(const float* __restrict__ x,
              const unsigned short* __restrict__ gof,
              const float* __restrict__ part,
              float* __restrict__ out) {
    __shared__ float rsum[NGRP];       // 4 KB only
    const int rb   = blockIdx.x;
    const int b    = (BATCH - 1) - (rb >> 1);
    const int half = rb & 1;
    const int t    = threadIdx.x;

    const float* __restrict__ prow = part + (size_t)b * NCHUNK * NGRP;
    float s = 0.0f;
    #pragma unroll
    for (int c = 0; c < NCHUNK; ++c) s += prow[c * NGRP + t];  // 8 indep loads
    rsum[t] = 1.0f / s;
    __syncthreads();

    const float4* __restrict__ xrow4 = (const float4*)(x + (size_t)b * NEUR);
    const u16x4*  __restrict__ gof4  = (const u16x4*)gof;  // 8 B per float4
    f32x4*        __restrict__ orow4 = (f32x4*)(out + (size_t)b * NEUR);

    #pragma unroll
    for (int it = 0; it < H_ITERS; ++it) {
        const int e = half * HALF_F4 + it * BLK + t;
        const float4 v = xrow4[e];     // L3-hot re-read
        const u16x4 g = gof4[e];       // 128 KB table, L2-resident
        f32x4 o;
        o.x = v.x * rsum[g.x];
        o.y = v.y * rsum[g.y];
        o.z = v.z * rsum[g.z];
        o.w = v.w * rsum[g.w];
        __builtin_nontemporal_store(o, &orow4[e]);  // don't evict x from L3
    }
}

extern "C" void kernel_launch(void* const* d_in, const int* in_sizes, int n_in,
                              void* d_out, int out_size, void* d_ws, size_t ws_size,
                              hipStream_t stream) {
    const float* x     = (const float*)d_in[0];
    const int*   index = (const int*)d_in[1];
    float*       out   = (float*)d_out;

    unsigned short* gof    = (unsigned short*)d_ws;                 // 128 KB
    unsigned short* bucket = gof + NEUR;                            // 256 KB
    float*          part   = (float*)(bucket + BUCKET_ELEMS);       // 32 MB
    unsigned int*   spill  = (unsigned int*)(part + (size_t)BATCH * NCHUNK * NGRP);

    hipMemsetAsync(spill, 0, sizeof(unsigned int), stream);  // zero spill count
    build_tables<<<NEUR / BLK, BLK, 0, stream>>>(index, gof, bucket, spill);
    k1_partial<<<BATCH * NCHUNK, BLK1, 0, stream>>>(x, bucket, spill, part);
    k3_scale<<<BATCH * 2, BLK, 0, stream>>>(x, gof, part, out);
}

// Round 14
// 147.182 us; speedup vs baseline: 1.1226x; 1.0127x over previous
//
#include <hip/hip_runtime.h>
#include <hip/hip_bf16.h>

// x: [B=1024, N=65536] f32, index: [N] i32 permutation, group size 64.
#define BATCH   1024
#define NEUR    65536
#define NGRP    1024
#define NCHUNK  8
#define CHUNK   (NEUR / NCHUNK)       // 8192 floats per chunk (32 KB LDS)
#define CHUNK_F4 (CHUNK / 4)          // 2048 float4
#define BLK1    512                   // k1 block: 4 blocks/CU (R13-proven)
#define F4T1    (CHUNK_F4 / BLK1)     // 4 float4 per thread
#define KMAX    16                    // padded slots per (chunk, group) cell
#define SENT    CHUNK                 // sentinel LDS slot holding 0.0f
#define BLK     1024                  // build/k3 block
#define ROW_F4  (NEUR / 4)            // 16384
#define HALF_F4 (ROW_F4 / 2)          // 8192
#define H_ITERS (HALF_F4 / BLK)       // 8
#define BUCKET_ELEMS (NCHUNK * NGRP * KMAX)   // 131072 u16 = 256 KB
#define SPILL_CAP 1024

typedef float          f32x4 __attribute__((ext_vector_type(4)));
typedef unsigned short u16x8 __attribute__((ext_vector_type(8)));
typedef unsigned short u16x4 __attribute__((ext_vector_type(4)));

// ws: [gof u16 128 KB][bucket 256 KB][part 32 MB][spill 4 KB]

// Wave == one group (64 consecutive permuted positions). Ballot/popcount
// slots each member into its source-chunk cell (transposed [cell][slot]);
// the wave also writes its own cells' pad sentinels (128 slots = 2 passes).
// Overflow (~25 entries chip-wide) -> spill list, handled in k1 from LDS.
__global__ void build_tables(const int* __restrict__ index,
                             unsigned short* __restrict__ gof,
                             unsigned short* __restrict__ bucket,
                             unsigned int* __restrict__ spill) {
    const int p    = blockIdx.x * blockDim.x + threadIdx.x;
    const int lane = threadIdx.x & 63;
    const int g    = p >> 6;
    const int s    = index[p];
    gof[s] = (unsigned short)g;
    const int c = s >> 13;                                 // s / CHUNK
    unsigned long long mc = 0;
    int count[NCHUNK];
    #pragma unroll
    for (int cc = 0; cc < NCHUNK; ++cc) {
        unsigned long long m = __ballot(c == cc);
        if (cc == c) mc = m;
        count[cc] = __popcll(m);
    }
    const int k = __popcll(mc & ((1ull << lane) - 1ull));
    if (k < KMAX) {
        bucket[((size_t)(c * NGRP + g)) * KMAX + k] = (unsigned short)(s & (CHUNK - 1));
    } else {
        unsigned int pos = atomicAdd(spill, 1u);
        if (pos < SPILL_CAP - 1)
            spill[1 + pos] = ((unsigned)g << 16) | (unsigned)s;  // s carries chunk
    }
    // Pad slots kk in [count_c, KMAX): 8 cells x 16 slots = 128 = 2 lane-passes.
    #pragma unroll
    for (int j = 0; j < 2; ++j) {
        const int slot = lane + j * 64;                    // 0..127
        const int cc = slot >> 4, kk = slot & 15;
        if (kk >= count[cc])
            bucket[((size_t)(cc * NGRP + g)) * KMAX + kk] = (unsigned short)SENT;
    }
}

// k1: one block per (row, chunk) — 8192 blocks, 512 threads, 32.8 KB LDS,
// 4 blocks/CU (R13-proven). R14 changes, both on the stage->gather critical
// path: (1) staging via global_load_lds width=16 (no VGPR round-trip; LDS
// dest is exactly wave-uniform-base + lane*16 so the DMA layout matches);
// (2) bucket u16x8 loads + spill count hoisted ABOVE the barrier so their
// L2 latency hides under the staging drain.
__global__ __launch_bounds__(BLK1, 8)
void k1_partial(const float* __restrict__ x,
                const unsigned short* __restrict__ bucket,
                const unsigned int* __restrict__ spill,
                float* __restrict__ part) {
    __shared__ float xs[CHUNK + 16];   // 32 KB chunk + sentinel
    const int bc = blockIdx.x;
    const int b  = bc >> 3;            // row
    const int c  = bc & 7;             // chunk
    const int t  = threadIdx.x;

    // Hoisted independent L2 loads (R14): in flight during staging.
    const unsigned short* __restrict__ bk0 =
        bucket + ((size_t)(c * NGRP + t)) * KMAX;          // 32 B contiguous
    const unsigned short* __restrict__ bk1 =
        bucket + ((size_t)(c * NGRP + t + 512)) * KMAX;
    const u16x8 w0 = *(const u16x8*)(bk0);
    const u16x8 w1 = *(const u16x8*)(bk0 + 8);
    const u16x8 w2 = *(const u16x8*)(bk1);
    const u16x8 w3 = *(const u16x8*)(bk1 + 8);
    const unsigned int ns = spill[0];

    if (t == 0) xs[SENT] = 0.0f;

    // Async global->LDS staging, width=16: lane l of wave w writes
    // xs4[i*512 + w*64 + l] = uniform base (i*512+w*64)*16 + l*16 bytes.
    const float4* __restrict__ src =
        (const float4*)(x + (size_t)b * NEUR + (size_t)c * CHUNK);
    float4* xs4 = (float4*)xs;
    #pragma unroll
    for (int i = 0; i < F4T1; ++i) {
        __builtin_amdgcn_global_load_lds(
            (const __attribute__((address_space(1))) unsigned int*)(src + i * BLK1 + t),
            (__attribute__((address_space(3))) unsigned int*)(xs4 + i * BLK1 + t),
            16, 0, 0);
    }
    __syncthreads();                   // drains vmcnt (DMA) + lgkmcnt (sentinel)

    // 16 branch-free sentinel-padded gather-adds per owned group (2 groups).
    float a0 = 0.0f, a1 = 0.0f, b0 = 0.0f, b1 = 0.0f;
    #pragma unroll
    for (int j = 0; j < 8; ++j) {
        a0 += xs[w0[j]];
        a1 += xs[w1[j]];
        b0 += xs[w2[j]];
        b1 += xs[w3[j]];               // pads hit the 0.0 sentinel
    }

    // Spill entries for THIS chunk: add from LDS (~25 chip-wide, wave scan).
    for (unsigned int e = 0; e < ns; ++e) {
        const unsigned int ent = spill[1 + e];
        if (((ent >> 13) & 7u) == (unsigned)c) {
            const float v = xs[ent & 0x1FFFu];
            const int gg = (int)(ent >> 16);
            if (gg == t)            a1 += v;
            else if (gg == t + 512) b1 += v;
        }
    }

    float* __restrict__ prow = part + ((size_t)b * NCHUNK + c) * NGRP;
    prow[t]       = a0 + a1;           // coalesced
    prow[t + 512] = b0 + b1;
}

// k3: one block per HALF-row (2048 blocks), reverse order so L3-hottest rows
// go first. 8 coalesced partial reads, reciprocal, then coalesced scale +
// nontemporal store (u16 group ids halve table traffic vs int32). UNCHANGED.
__global__ __launch_bounds__(BLK, 8)
void k3_scale(const float* __restrict__ x,
              const unsigned short* __restrict__ gof,
              const float* __restrict__ part,
              float* __restrict__ out) {
    __shared__ float rsum[NGRP];       // 4 KB only
    const int rb   = blockIdx.x;
    const int b    = (BATCH - 1) - (rb >> 1);
    const int half = rb & 1;
    const int t    = threadIdx.x;

    const float* __restrict__ prow = part + (size_t)b * NCHUNK * NGRP;
    float s = 0.0f;
    #pragma unroll
    for (int c = 0; c < NCHUNK; ++c) s += prow[c * NGRP + t];  // 8 indep loads
    rsum[t] = 1.0f / s;
    __syncthreads();

    const float4* __restrict__ xrow4 = (const float4*)(x + (size_t)b * NEUR);
    const u16x4*  __restrict__ gof4  = (const u16x4*)gof;  // 8 B per float4
    f32x4*        __restrict__ orow4 = (f32x4*)(out + (size_t)b * NEUR);

    #pragma unroll
    for (int it = 0; it < H_ITERS; ++it) {
        const int e = half * HALF_F4 + it * BLK + t;
        const float4 v = xrow4[e];     // L3-hot re-read
        const u16x4 g = gof4[e];       // 128 KB table, L2-resident
        f32x4 o;
        o.x = v.x * rsum[g.x];
        o.y = v.y * rsum[g.y];
        o.z = v.z * rsum[g.z];
        o.w = v.w * rsum[g.w];
        __builtin_nontemporal_store(o, &orow4[e]);  // don't evict x from L3
    }
}

extern "C" void kernel_launch(void* const* d_in, const int* in_sizes, int n_in,
                              void* d_out, int out_size, void* d_ws, size_t ws_size,
                              hipStream_t stream) {
    const float* x     = (const float*)d_in[0];
    const int*   index = (const int*)d_in[1];
    float*       out   = (float*)d_out;

    unsigned short* gof    = (unsigned short*)d_ws;                 // 128 KB
    unsigned short* bucket = gof + NEUR;                            // 256 KB
    float*          part   = (float*)(bucket + BUCKET_ELEMS);       // 32 MB
    unsigned int*   spill  = (unsigned int*)(part + (size_t)BATCH * NCHUNK * NGRP);

    hipMemsetAsync(spill, 0, sizeof(unsigned int), stream);  // zero spill count
    build_tables<<<NEUR / BLK, BLK, 0, stream>>>(index, gof, bucket, spill);
    k1_partial<<<BATCH * NCHUNK, BLK1, 0, stream>>>(x, bucket, spill, part);
    k3_scale<<<BATCH * 2, BLK, 0, stream>>>(x, gof, part, out);
}